// Round 4
// baseline (231.631 us; speedup 1.0000x reference)
//
#include <hip/hip_runtime.h>

#define B_  8
#define S_  1024
#define E_  512
#define H_  8
#define DK_ 64
#define TI  128
#define TJ  32

// One block = (b,h) x 128 i-rows. 256 threads: rg = t>>3 owns 4 rows,
// lo = t&7 owns an 8-wide d-slice. Single-pass softmax (scores in [0,1],
// exp in [1,e] -- no running max needed). Input fp32, output fp32.
__global__ __launch_bounds__(256) void attn_kernel(const float* __restrict__ x,
                                                   float* __restrict__ out) {
    const int bh = blockIdx.x;          // 0..63
    const int b  = bh >> 3, h = bh & 7;
    const int i0 = blockIdx.y * TI;
    const int t  = threadIdx.x;
    const int rg = t >> 3;              // 0..31 (row group of 4)
    const int lo = t & 7;               // 0..7

    __shared__ float sh_csj[TJ * 20];   // cos/sin interleaved, stride 20 (pad)
    __shared__ float sh_v [TJ * 64];    // V tile fp32
    __shared__ float sh_p [TJ * 132];   // transposed P: [jj][row], stride 132

    const float* xh = x + (size_t)b * S_ * E_ + h * DK_;

    // per-thread cos/sin for its 4 i-rows (8x lane redundancy, once per block)
    float ci[4][16];
    #pragma unroll
    for (int r = 0; r < 4; ++r) {
        const float* px = xh + (size_t)(i0 + rg * 4 + r) * E_;
        #pragma unroll
        for (int w = 0; w < 8; ++w) {
            float v = px[w] * 0.5f;
            ci[r][2 * w]     = __cosf(v);
            ci[r][2 * w + 1] = __sinf(v);
        }
    }

    float acc[4][8];
    #pragma unroll
    for (int r = 0; r < 4; ++r)
        #pragma unroll
        for (int d = 0; d < 8; ++d) acc[r][d] = 0.f;
    float denom[4] = {0.f, 0.f, 0.f, 0.f};

    for (int j0 = 0; j0 < S_; j0 += TJ) {
        __syncthreads();   // previous tile fully consumed

        // stage cos/sin for j-tile: thread (rg,lo) -> (jj=rg, w=lo)
        {
            float v = xh[(size_t)(j0 + rg) * E_ + lo] * 0.5f;
            sh_csj[rg * 20 + 2 * lo]     = __cosf(v);
            sh_csj[rg * 20 + 2 * lo + 1] = __sinf(v);
        }
        // stage V tile: thread (rg,lo) -> row jj=rg, 8 floats at col lo*8
        {
            const float* src = xh + (size_t)(j0 + rg) * E_ + lo * 8;
            const float4 a = ((const float4*)src)[0];
            const float4 c = ((const float4*)src)[1];
            float* dst = sh_v + rg * 64 + lo * 8;
            *(float4*)(dst)     = a;
            *(float4*)(dst + 4) = c;
        }
        __syncthreads();

        // phase 1: scores for rows rg*4+{0..3} x jj = lo+8p
        #pragma unroll
        for (int p = 0; p < 4; ++p) {
            const int jj = lo + 8 * p;
            const float* cj = sh_csj + jj * 20;
            const float4 c0 = *(const float4*)(cj);
            const float4 c1 = *(const float4*)(cj + 4);
            const float4 c2 = *(const float4*)(cj + 8);
            const float4 c3 = *(const float4*)(cj + 12);
            float4 o4;
            float* po = &o4.x;
            #pragma unroll
            for (int r = 0; r < 4; ++r) {
                const float* c = ci[r];
                float p0 = c[0]  * c0.x + c[1]  * c0.y;
                float p1 = c[2]  * c0.z + c[3]  * c0.w;
                float p2 = c[4]  * c1.x + c[5]  * c1.y;
                float p3 = c[6]  * c1.z + c[7]  * c1.w;
                float p4 = c[8]  * c2.x + c[9]  * c2.y;
                float p5 = c[10] * c2.z + c[11] * c2.w;
                float p6 = c[12] * c3.x + c[13] * c3.y;
                float p7 = c[14] * c3.z + c[15] * c3.w;
                float prod = ((p0 * p1) * (p2 * p3)) * ((p4 * p5) * (p6 * p7));
                po[r] = __expf(__builtin_fabsf(prod));
            }
            *(float4*)(sh_p + jj * 132 + rg * 4) = o4;
        }
        __syncthreads();

        // phase 2: acc[r][d] += P[jj][row] * V[jj][d]
        #pragma unroll 8
        for (int jj = 0; jj < TJ; ++jj) {
            const float4 pw = *(const float4*)(sh_p + jj * 132 + rg * 4);
            const float* vr = sh_v + jj * 64 + lo * 8;
            const float4 v0 = *(const float4*)(vr);
            const float4 v1 = *(const float4*)(vr + 4);
            const float* pv = &pw.x;
            #pragma unroll
            for (int r = 0; r < 4; ++r) {
                const float w = pv[r];
                denom[r] += w;
                acc[r][0] += w * v0.x; acc[r][1] += w * v0.y;
                acc[r][2] += w * v0.z; acc[r][3] += w * v0.w;
                acc[r][4] += w * v1.x; acc[r][5] += w * v1.y;
                acc[r][6] += w * v1.z; acc[r][7] += w * v1.w;
            }
        }
    }

    #pragma unroll
    for (int r = 0; r < 4; ++r) {
        const float inv = 1.f / denom[r];
        float* o = out + (size_t)(b * S_ + i0 + rg * 4 + r) * E_ + h * DK_ + lo * 8;
        float4 o0, o1;
        o0.x = acc[r][0] * inv; o0.y = acc[r][1] * inv;
        o0.z = acc[r][2] * inv; o0.w = acc[r][3] * inv;
        o1.x = acc[r][4] * inv; o1.y = acc[r][5] * inv;
        o1.z = acc[r][6] * inv; o1.w = acc[r][7] * inv;
        ((float4*)o)[0] = o0;
        ((float4*)o)[1] = o1;
    }
}

extern "C" void kernel_launch(void* const* d_in, const int* in_sizes, int n_in,
                              void* d_out, int out_size, void* d_ws, size_t ws_size,
                              hipStream_t stream) {
    const float* x = (const float*)d_in[0];
    float* out = (float*)d_out;
    attn_kernel<<<dim3(B_ * H_, S_ / TI), 256, 0, stream>>>(x, out);
}

// Round 5
// 138.637 us; speedup vs baseline: 1.6708x; 1.6708x over previous
//
#include <hip/hip_runtime.h>

#define B_  8
#define S_  1024
#define E_  512
#define TI  128
#define TJ  32

#define P_STRIDE  40   // halves per row (80B, 16B-aligned rows)
#define V_STRIDE  40   // halves per row
#define CJ_STRIDE 20   // floats per row (80B)

typedef _Float16 half_t;
typedef _Float16 half4 __attribute__((ext_vector_type(4)));
typedef _Float16 half8 __attribute__((ext_vector_type(8)));
typedef float    floatx16 __attribute__((ext_vector_type(16)));

// Block = (b,h) x 128 i-rows, 256 threads = 4 waves.
// Phase 1 (VALU): thread (rg=t>>3, lo=t&7) computes exp|prod cos| for
//   i = rg*4+r (r<4), j = lo*4+jj (jj<4), fp32, writes f16 P-tile to LDS.
// Phase 2 (MFMA): wave wv owns i-rows wv*32..+31; P[32x32] x V[32x64] via
//   4x v_mfma_f32_32x32x16_f16 (A=P from LDS, B=V^T from LDS).
__global__ __launch_bounds__(256, 2) void attn_kernel(const float* __restrict__ x,
                                                      float* __restrict__ out) {
    const int bh = blockIdx.x;
    const int b  = bh >> 3, h = bh & 7;
    const int i0 = blockIdx.y * TI;
    const int t  = threadIdx.x;
    const int rg = t >> 3;              // 0..31
    const int lo = t & 7;               // 0..7
    const int wv = t >> 6;              // wave 0..3
    const int ln = t & 63;              // lane
    const int m  = ln & 31;             // MFMA row/col index
    const int hf = ln >> 5;             // lane half

    __shared__ __align__(16) half_t sh_p[TI * P_STRIDE];    // P tile f16 [i][j]
    __shared__ __align__(16) half_t sh_v[64 * V_STRIDE];    // V^T f16 [d][j]
    __shared__ __align__(16) float  sh_cj[TJ * CJ_STRIDE];  // trig [j'][16]
    __shared__ float sh_den[TI];

    const float* xh = x + (size_t)b * S_ * E_ + h * 64;

    // trig for this thread's 4 i-rows (once per block)
    float ci[4][16];
    #pragma unroll
    for (int r = 0; r < 4; ++r) {
        const float* px = xh + (size_t)(i0 + rg * 4 + r) * E_;
        #pragma unroll
        for (int w = 0; w < 8; ++w) {
            float v = px[w] * 0.5f;
            ci[r][2 * w]     = __cosf(v);
            ci[r][2 * w + 1] = __sinf(v);
        }
    }

    floatx16 acc0, acc1;
    #pragma unroll
    for (int k = 0; k < 16; ++k) { acc0[k] = 0.f; acc1[k] = 0.f; }
    float dpart[4] = {0.f, 0.f, 0.f, 0.f};

    const int sj_j = t & 31, sj_w = t >> 5;   // cj staging assignment
    const int sv_j = t >> 3, sv_d0 = lo * 8;  // V staging assignment

    for (int j0 = 0; j0 < S_; j0 += TJ) {
        __syncthreads();   // previous tile fully consumed

        // stage cj trig; physical row (j&3)*8 + (j>>2) so phase-1 reads
        // (rows lo*4+jj -> phys jj*8+lo) are bank-conflict-free
        {
            float v = xh[(size_t)(j0 + sj_j) * E_ + sj_w] * 0.5f;
            int pr = ((sj_j & 3) << 3) | (sj_j >> 2);
            float2 cs; cs.x = __cosf(v); cs.y = __sinf(v);
            *(float2*)&sh_cj[pr * CJ_STRIDE + 2 * sj_w] = cs;
        }
        // stage V^T f16: row d, col j; per-lane permuted row order breaks
        // the stride-aliasing bank pattern (d0=8*lo aliases mod 32 banks)
        {
            const float* src = xh + (size_t)(j0 + sv_j) * E_ + sv_d0;
            float4 a = ((const float4*)src)[0];
            float4 c = ((const float4*)src)[1];
            float vals[8] = {a.x, a.y, a.z, a.w, c.x, c.y, c.z, c.w};
            #pragma unroll
            for (int n = 0; n < 8; ++n) {
                int q = (n + lo) & 7;
                sh_v[(sv_d0 + q) * V_STRIDE + sv_j] = (half_t)vals[q];
            }
        }
        __syncthreads();

        // phase 1: fp32 scores -> exp -> f16 P tile
        float sc[4][4];
        #pragma unroll
        for (int jj = 0; jj < 4; ++jj) {
            const float* cj = &sh_cj[(jj * 8 + lo) * CJ_STRIDE];
            float4 c0 = *(const float4*)(cj);
            float4 c1 = *(const float4*)(cj + 4);
            float4 c2 = *(const float4*)(cj + 8);
            float4 c3 = *(const float4*)(cj + 12);
            #pragma unroll
            for (int r = 0; r < 4; ++r) {
                const float* c = ci[r];
                float p0 = c[0]  * c0.x + c[1]  * c0.y;
                float p1 = c[2]  * c0.z + c[3]  * c0.w;
                float p2 = c[4]  * c1.x + c[5]  * c1.y;
                float p3 = c[6]  * c1.z + c[7]  * c1.w;
                float p4 = c[8]  * c2.x + c[9]  * c2.y;
                float p5 = c[10] * c2.z + c[11] * c2.w;
                float p6 = c[12] * c3.x + c[13] * c3.y;
                float p7 = c[14] * c3.z + c[15] * c3.w;
                float prod = ((p0 * p1) * (p2 * p3)) * ((p4 * p5) * (p6 * p7));
                sc[r][jj] = __expf(__builtin_fabsf(prod));
            }
        }
        #pragma unroll
        for (int r = 0; r < 4; ++r) {
            dpart[r] += (sc[r][0] + sc[r][1]) + (sc[r][2] + sc[r][3]);
            half4 pk;
            pk[0] = (half_t)sc[r][0]; pk[1] = (half_t)sc[r][1];
            pk[2] = (half_t)sc[r][2]; pk[3] = (half_t)sc[r][3];
            *(half4*)&sh_p[(rg * 4 + r) * P_STRIDE + lo * 4] = pk;
        }
        __syncthreads();

        // phase 2: MFMA PV. A[m=i][k=j=hf*8+t], B[k=j][n=d], K=16 per mfma.
        {
            const half_t* prow = &sh_p[(wv * 32 + m) * P_STRIDE];
            half8 a0 = *(const half8*)(prow + hf * 8);         // j 0..15
            half8 a1 = *(const half8*)(prow + 16 + hf * 8);    // j 16..31
            const half_t* vr0 = &sh_v[m * V_STRIDE];           // d = m
            const half_t* vr1 = &sh_v[(32 + m) * V_STRIDE];    // d = 32+m
            half8 b00 = *(const half8*)(vr0 + hf * 8);
            half8 b01 = *(const half8*)(vr0 + 16 + hf * 8);
            half8 b10 = *(const half8*)(vr1 + hf * 8);
            half8 b11 = *(const half8*)(vr1 + 16 + hf * 8);
            acc0 = __builtin_amdgcn_mfma_f32_32x32x16_f16(a0, b00, acc0, 0, 0, 0);
            acc0 = __builtin_amdgcn_mfma_f32_32x32x16_f16(a1, b01, acc0, 0, 0, 0);
            acc1 = __builtin_amdgcn_mfma_f32_32x32x16_f16(a0, b10, acc1, 0, 0, 0);
            acc1 = __builtin_amdgcn_mfma_f32_32x32x16_f16(a1, b11, acc1, 0, 0, 0);
        }
    }

    // denominator: reduce over the 8 threads (lo) sharing each i-row
    #pragma unroll
    for (int r = 0; r < 4; ++r) {
        float v = dpart[r];
        v += __shfl_xor(v, 1, 64);
        v += __shfl_xor(v, 2, 64);
        v += __shfl_xor(v, 4, 64);
        dpart[r] = v;
    }
    if (lo == 0) {
        float4 dd;
        dd.x = dpart[0]; dd.y = dpart[1]; dd.z = dpart[2]; dd.w = dpart[3];
        *(float4*)&sh_den[rg * 4] = dd;
    }
    __syncthreads();

    // epilogue: D[i=(reg&3)+8*(reg>>2)+4*hf][d=m], divide by denom, store
    #pragma unroll
    for (int t4 = 0; t4 < 16; ++t4) {
        int il = (t4 & 3) + 8 * (t4 >> 2) + 4 * hf;
        float inv = 1.f / sh_den[wv * 32 + il];
        size_t base = ((size_t)(b * S_ + i0 + wv * 32 + il)) * E_ + h * 64 + m;
        out[base]      = acc0[t4] * inv;
        out[base + 32] = acc1[t4] * inv;
    }
}

extern "C" void kernel_launch(void* const* d_in, const int* in_sizes, int n_in,
                              void* d_out, int out_size, void* d_ws, size_t ws_size,
                              hipStream_t stream) {
    const float* x = (const float*)d_in[0];
    float* out = (float*)d_out;
    attn_kernel<<<dim3(B_ * 8, S_ / TI), 256, 0, stream>>>(x, out);
}

// Round 6
// 111.719 us; speedup vs baseline: 2.0733x; 1.2409x over previous
//
#include <hip/hip_runtime.h>

#define B_  8
#define S_  1024
#define E_  512
#define TI  128
#define TJ  32
#define P_STR 40   // halves; rows 80B -> b64/b128 aligned
#define V_STR 40

typedef _Float16 half_t;
typedef _Float16 half4_t __attribute__((ext_vector_type(4)));
typedef _Float16 half8_t __attribute__((ext_vector_type(8)));
typedef float    floatx16 __attribute__((ext_vector_type(16)));

// Build this lane's MFMA fragment (8 f16) of the rank-16 feature maps:
//   L[kk] = prod_{w<4} trig_w(kk bits), H[kk] = prod_{w>=4} trig_w
// Lane holds kk = hf*8 + idx. score(i,j) = (Li.Lj)*(Hi.Hj).
__device__ __forceinline__ void make_frags(float4 w0, float4 w1, int hf,
                                           half8_t* fH, half8_t* fL) {
    float xi[8] = {w0.x, w0.y, w0.z, w0.w, w1.x, w1.y, w1.z, w1.w};
    float c[8], s[8];
    #pragma unroll
    for (int w = 0; w < 8; ++w) {
        float v = xi[w] * 0.5f;
        c[w] = __cosf(v);
        s[w] = __sinf(v);
    }
    float p01[4] = {c[0]*c[1], s[0]*c[1], c[0]*s[1], s[0]*s[1]};
    float p23[4] = {c[2]*c[3], s[2]*c[3], c[2]*s[3], s[2]*s[3]};
    float p45[4] = {c[4]*c[5], s[4]*c[5], c[4]*s[5], s[4]*s[5]};
    float p67[4] = {c[6]*c[7], s[6]*c[7], c[6]*s[7], s[6]*s[7]};
    #pragma unroll
    for (int idx = 0; idx < 8; ++idx) {
        int a = idx & 3;
        int bsel = (idx >> 2) | (hf << 1);
        (*fL)[idx] = (half_t)(p01[a] * p23[bsel]);
        (*fH)[idx] = (half_t)(p45[a] * p67[bsel]);
    }
}

// Block = (b,h) x 128 i-rows, 256 threads = 4 waves; wave wv owns i-cols
// wv*32..+31. Per 32-row j-tile:
//   S^T[j][i] = mfma(Hj,Hi) .* mfma(Lj,Li)   (2 MFMAs, frags in registers)
//   P = exp|S| -> f16 -> LDS [i][j] (b64 writes; own-wave rows only)
//   O += P x V via 4 MFMAs (A=P, B=V^T from LDS)
// Denominator: per-lane scalar (C-layout col = i), one shfl at the end.
__global__ __launch_bounds__(256, 2) void attn_kernel(const float* __restrict__ x,
                                                      float* __restrict__ out) {
    const int bh = blockIdx.x;
    const int b  = bh >> 3, h = bh & 7;
    const int i0 = blockIdx.y * TI;
    const int t  = threadIdx.x;
    const int wv = t >> 6;
    const int ln = t & 63;
    const int m  = ln & 31;
    const int hf = ln >> 5;
    const int lo = t & 7;

    __shared__ __align__(16) half_t sh_p[TI * P_STR];
    __shared__ __align__(16) half_t sh_v[64 * V_STR];
    __shared__ float sh_den[TI];

    const float* xh = x + (size_t)b * S_ * E_ + h * 64;

    // B-side fragments (Phi_i), i = i0 + wv*32 + m  — once per kernel
    half8_t biH, biL;
    {
        const float* px = xh + (size_t)(i0 + wv * 32 + m) * E_;
        float4 w0 = ((const float4*)px)[0];
        float4 w1 = ((const float4*)px)[1];
        make_frags(w0, w1, hf, &biH, &biL);
    }

    floatx16 acc0, acc1, z;
    #pragma unroll
    for (int k = 0; k < 16; ++k) { acc0[k] = 0.f; acc1[k] = 0.f; z[k] = 0.f; }
    float dacc = 0.f;

    const int sv_j  = t >> 3;     // V staging: row j
    const int sv_d0 = lo * 8;     // V staging: first d

    for (int j0 = 0; j0 < S_; j0 += TJ) {
        __syncthreads();   // previous tile's LDS fully consumed

        // global loads (L1/L2-resident after first pass over x)
        const float* pj = xh + (size_t)(j0 + m) * E_;
        float4 jw0 = ((const float4*)pj)[0];
        float4 jw1 = ((const float4*)pj)[1];
        const float* pv = xh + (size_t)(j0 + sv_j) * E_ + sv_d0;
        float4 v0 = ((const float4*)pv)[0];
        float4 v1 = ((const float4*)pv)[1];

        // A-side fragments (Phi_j), j = j0 + m — registers only
        half8_t ajH, ajL;
        make_frags(jw0, jw1, hf, &ajH, &ajL);

        // V^T staging (f16), per-lane permuted row order vs bank aliasing
        {
            float vals[8] = {v0.x, v0.y, v0.z, v0.w, v1.x, v1.y, v1.z, v1.w};
            #pragma unroll
            for (int nq = 0; nq < 8; ++nq) {
                int q = (nq + lo) & 7;
                sh_v[(sv_d0 + q) * V_STR + sv_j] = (half_t)vals[q];
            }
        }
        __syncthreads();   // sh_v ready for all waves

        // scores, transposed: lane holds S^T[j=(r&3)+8g+4hf][i=wv*32+m]
        floatx16 sH = __builtin_amdgcn_mfma_f32_32x32x16_f16(ajH, biH, z, 0, 0, 0);
        floatx16 sL = __builtin_amdgcn_mfma_f32_32x32x16_f16(ajL, biL, z, 0, 0, 0);

        // exp|s| -> f16 P-tile [i][j]; 4 consecutive j per b64 write
        const int irow = wv * 32 + m;
        #pragma unroll
        for (int g = 0; g < 4; ++g) {
            half4_t pk;
            #pragma unroll
            for (int r = 0; r < 4; ++r) {
                float sc = sH[4 * g + r] * sL[4 * g + r];
                float p = __expf(__builtin_fabsf(sc));
                dacc += p;
                pk[r] = (half_t)p;
            }
            *(half4_t*)&sh_p[irow * P_STR + g * 8 + hf * 4] = pk;
        }
        // own-wave rows only -> no barrier needed before PV A-reads

        // PV: A = P[i][k=j], B = V^T[d][k=j]
        const half_t* prow = &sh_p[(wv * 32 + m) * P_STR];
        half8_t ap0 = *(const half8_t*)(prow + hf * 8);
        half8_t ap1 = *(const half8_t*)(prow + 16 + hf * 8);
        const half_t* vr0 = &sh_v[m * V_STR];
        const half_t* vr1 = &sh_v[(32 + m) * V_STR];
        half8_t b00 = *(const half8_t*)(vr0 + hf * 8);
        half8_t b01 = *(const half8_t*)(vr0 + 16 + hf * 8);
        half8_t b10 = *(const half8_t*)(vr1 + hf * 8);
        half8_t b11 = *(const half8_t*)(vr1 + 16 + hf * 8);
        acc0 = __builtin_amdgcn_mfma_f32_32x32x16_f16(ap0, b00, acc0, 0, 0, 0);
        acc0 = __builtin_amdgcn_mfma_f32_32x32x16_f16(ap1, b01, acc0, 0, 0, 0);
        acc1 = __builtin_amdgcn_mfma_f32_32x32x16_f16(ap0, b10, acc1, 0, 0, 0);
        acc1 = __builtin_amdgcn_mfma_f32_32x32x16_f16(ap1, b11, acc1, 0, 0, 0);
    }

    // denominator: lane's dacc covers half the j's for i = wv*32+m
    dacc += __shfl_xor(dacc, 32, 64);
    sh_den[wv * 32 + m] = dacc;    // both hf halves write same value
    __syncthreads();

    // epilogue: O C-layout row il, col d=m / m+32
    #pragma unroll
    for (int reg = 0; reg < 16; ++reg) {
        int il = (reg & 3) + 8 * (reg >> 2) + 4 * hf;
        float inv = 1.f / sh_den[wv * 32 + il];
        size_t base = ((size_t)(b * S_ + i0 + wv * 32 + il)) * E_ + h * 64 + m;
        out[base]      = acc0[reg] * inv;
        out[base + 32] = acc1[reg] * inv;
    }
}

extern "C" void kernel_launch(void* const* d_in, const int* in_sizes, int n_in,
                              void* d_out, int out_size, void* d_ws, size_t ws_size,
                              hipStream_t stream) {
    const float* x = (const float*)d_in[0];
    float* out = (float*)d_out;
    attn_kernel<<<dim3(B_ * 8, S_ / TI), 256, 0, stream>>>(x, out);
}